// Round 1
// baseline (335.253 us; speedup 1.0000x reference)
//
#include <hip/hip_runtime.h>

#define NB 8
#define NS 4
#define NN 8192
#define NM 50
#define K10 10
#define THREADS 256
#define COST_THRESH 50.0f

__device__ __forceinline__ bool lexless(float d1, int i1, float d2, int i2) {
  // matches jax.lax.top_k ordering on -dist: (dist asc, index asc)
  return (d1 < d2) || (d1 == d2 && i1 < i2);
}

__global__ void __launch_bounds__(256) init_kernel(int* __restrict__ assign,
                                                   float* __restrict__ acc,
                                                   int* __restrict__ npos,
                                                   int* __restrict__ bs_unm) {
  int i = blockIdx.x * blockDim.x + threadIdx.x;
  const int total = NB * NS * NN;
  for (int j = i; j < total; j += gridDim.x * blockDim.x) assign[j] = -1;
  if (i < 4) acc[i] = 0.0f;
  if (i == 4) *npos = 0;
  if (i >= 8 && i < 8 + NB * NS) bs_unm[i - 8] = 0;
}

// One block per (b, s, m): raw top-10 nearest preds by (dist, idx).
// masked top-10 = {entries with dist < 50} (subset property), top-5 raw = first 5.
__global__ void __launch_bounds__(256) topk_kernel(
    const float* __restrict__ pred_boxes, const float* __restrict__ pred_scores,
    const float* __restrict__ gt_boxes, const int* __restrict__ n_gt,
    int* __restrict__ assign, float* __restrict__ per_gt_sum,
    int* __restrict__ bs_unm) {
  const int blk = blockIdx.x;      // b*NS*NM + s*NM + m
  const int m = blk % NM;
  const int bs = blk / NM;
  const int b = bs / NS;
  const int t = threadIdx.x;

  const float gx = gt_boxes[(b * NM + m) * 7 + 0];
  const float gy = gt_boxes[(b * NM + m) * 7 + 1];
  const float gz = gt_boxes[(b * NM + m) * 7 + 2];
  const bool valid = (m < n_gt[b]);

  // per-thread top-10, ascending; static indexing only (stays in VGPRs)
  float d[K10];
  int id[K10];
#pragma unroll
  for (int k = 0; k < K10; k++) { d[k] = INFINITY; id[k] = 0x7FFFFFFF; }

  const float* pb = pred_boxes + (size_t)bs * NN * 7;
  for (int n = t; n < NN; n += THREADS) {
    float dx = pb[n * 7 + 0] - gx;
    float dy = pb[n * 7 + 1] - gy;
    float dz = pb[n * 7 + 2] - gz;
    float dist = sqrtf(dx * dx + dy * dy + dz * dz);
    if (lexless(dist, n, d[K10 - 1], id[K10 - 1])) {
      float cd = dist;
      int ci = n;
#pragma unroll
      for (int k = 0; k < K10; k++) {
        bool lt = lexless(cd, ci, d[k], id[k]);
        float td = d[k]; int ti = id[k];
        if (lt) { d[k] = cd; id[k] = ci; cd = td; ci = ti; }
      }
    }
  }

  __shared__ float sd[THREADS * K10];
  __shared__ int si[THREADS * K10];
#pragma unroll
  for (int k = 0; k < K10; k++) { sd[t * K10 + k] = d[k]; si[t * K10 + k] = id[k]; }
  __syncthreads();

  // merge-tree of sorted 10-lists; thread t merges slots t and t+stride into t
  for (int stride = THREADS / 2; stride >= 1; stride >>= 1) {
    if (t < stride) {
      float md[K10]; int mi[K10];
      const float* da = &sd[t * K10];
      const int* ia = &si[t * K10];
      const float* db = &sd[(t + stride) * K10];
      const int* ib = &si[(t + stride) * K10];
      int i = 0, j = 0;
#pragma unroll
      for (int k = 0; k < K10; k++) {
        float va = da[i], vb = db[j];
        int xa = ia[i], xb = ib[j];
        bool ta = lexless(va, xa, vb, xb);
        md[k] = ta ? va : vb;
        mi[k] = ta ? xa : xb;
        i += ta ? 1 : 0;
        j += ta ? 0 : 1;
      }
#pragma unroll
      for (int k = 0; k < K10; k++) { sd[t * K10 + k] = md[k]; si[t * K10 + k] = mi[k]; }
    }
    __syncthreads();
  }

  if (t == 0) {
    bool matched = false;
#pragma unroll
    for (int k = 0; k < K10; k++) {
      if (valid && sd[k] < COST_THRESH) {
        matched = true;
        atomicMax(&assign[(size_t)bs * NN + si[k]], m);
      }
    }
    if (valid && !matched) {
      const float* ps = pred_scores + (size_t)bs * NN;
      float a = 0.0f;
#pragma unroll
      for (int k = 0; k < 5; k++) a += expf(-0.5f * sd[k]) * (1.0f - ps[si[k]]);
      atomicAdd(per_gt_sum, a * 0.2f);
      atomicOr(&bs_unm[bs], 1);
    }
  }
}

__global__ void __launch_bounds__(256) loss_kernel(
    const float* __restrict__ pred_boxes, const float* __restrict__ pred_scores,
    const float* __restrict__ gt_boxes, const int* __restrict__ assign,
    float* __restrict__ acc, int* __restrict__ npos) {
  int tid = blockIdx.x * blockDim.x + threadIdx.x;
  const int total = NB * NS * NN;
  float lc = 0.0f, spp = 0.0f, spn = 0.0f;
  int np = 0;
  for (int i = tid; i < total; i += gridDim.x * blockDim.x) {
    int a = assign[i];
    float x = pred_scores[i];
    if (a >= 0) {
      np++;
      int b = i / (NS * NN);
      const float* pbp = &pred_boxes[(size_t)i * 7];
      const float* gbp = &gt_boxes[(b * NM + a) * 7];
#pragma unroll
      for (int c = 0; c < 3; c++) {
        float diff = pbp[c] - gbp[c];
        float ad = fabsf(diff);
        lc += (ad < 1.0f) ? 0.5f * ad * ad : (ad - 0.5f);
      }
      // softplus(-x) = log1p(exp(-|x|)) + max(-x, 0)
      spp += log1pf(expf(-fabsf(x))) + fmaxf(-x, 0.0f);
    } else {
      // softplus(x) = log1p(exp(-|x|)) + max(x, 0)
      spn += log1pf(expf(-fabsf(x))) + fmaxf(x, 0.0f);
    }
  }
  // wave-64 shuffle reduce
  for (int off = 32; off >= 1; off >>= 1) {
    lc += __shfl_down(lc, off);
    spp += __shfl_down(spp, off);
    spn += __shfl_down(spn, off);
    np += __shfl_down(np, off);
  }
  if ((threadIdx.x & 63) == 0) {
    atomicAdd(&acc[1], lc);
    atomicAdd(&acc[2], spp);
    atomicAdd(&acc[3], spn);
    atomicAdd(npos, np);
  }
}

__global__ void final_kernel(const float* __restrict__ acc, const int* __restrict__ npos,
                             const int* __restrict__ bs_unm,
                             const float* __restrict__ wc, const float* __restrict__ wo,
                             const float* __restrict__ wu, float* __restrict__ out) {
  if (threadIdx.x == 0 && blockIdx.x == 0) {
    int ne = 0;
    for (int i = 0; i < NB * NS; i++) ne += bs_unm[i];
    float n_pos = (float)(*npos);
    float loss_center = acc[1] / fmaxf(n_pos * 3.0f, 1.0f);
    float n_neg = (float)(NB * NS * NN) - n_pos;
    float pw = fminf(10.0f, n_neg / fmaxf(n_pos, 1.0f));
    float loss_obj = (pw * acc[2] + acc[3]) / (float)(NB * NS * NN);
    float loss_unm = acc[0] / fmaxf((float)ne, 1.0f);
    out[0] = loss_center * wc[0] + loss_obj * wo[0] + loss_unm * wu[0];
  }
}

extern "C" void kernel_launch(void* const* d_in, const int* in_sizes, int n_in,
                              void* d_out, int out_size, void* d_ws, size_t ws_size,
                              hipStream_t stream) {
  const float* pred_boxes = (const float*)d_in[0];
  // d_in[1] = pred_classes (unused), d_in[4] = gt_classes (unused), d_in[9] = epoch (unused)
  const float* pred_scores = (const float*)d_in[2];
  const float* gt_boxes = (const float*)d_in[3];
  const int* n_gt = (const int*)d_in[5];
  const float* wc = (const float*)d_in[6];
  const float* wo = (const float*)d_in[7];
  const float* wu = (const float*)d_in[8];
  float* out = (float*)d_out;

  int* assign = (int*)d_ws;                                        // NB*NS*NN ints (1 MB)
  float* acc = (float*)((char*)d_ws + (size_t)NB * NS * NN * 4);   // [0]=per_gt,[1]=lc,[2]=spp,[3]=spn
  int* npos = (int*)(acc + 4);
  int* bs_unm = npos + 1;                                          // NB*NS ints

  init_kernel<<<256, 256, 0, stream>>>(assign, acc, npos, bs_unm);
  topk_kernel<<<NB * NS * NM, THREADS, 0, stream>>>(pred_boxes, pred_scores, gt_boxes,
                                                    n_gt, assign, &acc[0], bs_unm);
  loss_kernel<<<1024, 256, 0, stream>>>(pred_boxes, pred_scores, gt_boxes, assign, acc, npos);
  final_kernel<<<1, 64, 0, stream>>>(acc, npos, bs_unm, wc, wo, wu, out);
}

// Round 2
// 134.497 us; speedup vs baseline: 2.4926x; 2.4926x over previous
//
#include <hip/hip_runtime.h>

#define NB 8
#define NS 4
#define NN 8192
#define NM 50
#define K10 10
#define THREADS 256
#define COST_THRESH 50.0f
#define LOSS_BLOCKS 256

__device__ __forceinline__ bool lexless(float d1, int i1, float d2, int i2) {
  // matches jax.lax.top_k ordering on -dist: (dist asc, index asc)
  return (d1 < d2) || (d1 == d2 && i1 < i2);
}

__global__ void __launch_bounds__(256) init_kernel(int* __restrict__ assign,
                                                   float* __restrict__ acc,
                                                   int* __restrict__ bs_unm) {
  int i = blockIdx.x * blockDim.x + threadIdx.x;
  const int total = NB * NS * NN;
  for (int j = i; j < total; j += gridDim.x * blockDim.x) assign[j] = -1;
  if (i == 0) acc[0] = 0.0f;  // per_gt_sum
  if (i >= 8 && i < 8 + NB * NS) bs_unm[i - 8] = 0;
}

// One block per (b, s, m): raw top-10 nearest preds by (dist, idx).
// masked top-10 = {entries with dist < 50} (subset property), top-5 raw = first 5.
__global__ void __launch_bounds__(256) topk_kernel(
    const float* __restrict__ pred_boxes, const float* __restrict__ pred_scores,
    const float* __restrict__ gt_boxes, const int* __restrict__ n_gt,
    int* __restrict__ assign, float* __restrict__ per_gt_sum,
    int* __restrict__ bs_unm) {
  const int blk = blockIdx.x;      // b*NS*NM + s*NM + m
  const int m = blk % NM;
  const int bs = blk / NM;
  const int b = bs / NS;
  const int t = threadIdx.x;

  const float gx = gt_boxes[(b * NM + m) * 7 + 0];
  const float gy = gt_boxes[(b * NM + m) * 7 + 1];
  const float gz = gt_boxes[(b * NM + m) * 7 + 2];
  const bool valid = (m < n_gt[b]);

  // per-thread top-10, ascending; static indexing only (stays in VGPRs)
  float d[K10];
  int id[K10];
#pragma unroll
  for (int k = 0; k < K10; k++) { d[k] = INFINITY; id[k] = 0x7FFFFFFF; }

  const float* pb = pred_boxes + (size_t)bs * NN * 7;
  for (int n = t; n < NN; n += THREADS) {
    float dx = pb[n * 7 + 0] - gx;
    float dy = pb[n * 7 + 1] - gy;
    float dz = pb[n * 7 + 2] - gz;
    float dist = sqrtf(dx * dx + dy * dy + dz * dz);
    if (lexless(dist, n, d[K10 - 1], id[K10 - 1])) {
      float cd = dist;
      int ci = n;
#pragma unroll
      for (int k = 0; k < K10; k++) {
        bool lt = lexless(cd, ci, d[k], id[k]);
        float td = d[k]; int ti = id[k];
        if (lt) { d[k] = cd; id[k] = ci; cd = td; ci = ti; }
      }
    }
  }

  __shared__ float sd[THREADS * K10];
  __shared__ int si[THREADS * K10];
#pragma unroll
  for (int k = 0; k < K10; k++) { sd[t * K10 + k] = d[k]; si[t * K10 + k] = id[k]; }
  __syncthreads();

  // merge-tree of sorted 10-lists; thread t merges slots t and t+stride into t
  for (int stride = THREADS / 2; stride >= 1; stride >>= 1) {
    if (t < stride) {
      float md[K10]; int mi[K10];
      const float* da = &sd[t * K10];
      const int* ia = &si[t * K10];
      const float* db = &sd[(t + stride) * K10];
      const int* ib = &si[(t + stride) * K10];
      int i = 0, j = 0;
#pragma unroll
      for (int k = 0; k < K10; k++) {
        float va = da[i], vb = db[j];
        int xa = ia[i], xb = ib[j];
        bool ta = lexless(va, xa, vb, xb);
        md[k] = ta ? va : vb;
        mi[k] = ta ? xa : xb;
        i += ta ? 1 : 0;
        j += ta ? 0 : 1;
      }
#pragma unroll
      for (int k = 0; k < K10; k++) { sd[t * K10 + k] = md[k]; si[t * K10 + k] = mi[k]; }
    }
    __syncthreads();
  }

  if (t == 0) {
    bool matched = false;
#pragma unroll
    for (int k = 0; k < K10; k++) {
      if (valid && sd[k] < COST_THRESH) {
        matched = true;
        atomicMax(&assign[(size_t)bs * NN + si[k]], m);
      }
    }
    if (valid && !matched) {
      const float* ps = pred_scores + (size_t)bs * NN;
      float a = 0.0f;
#pragma unroll
      for (int k = 0; k < 5; k++) a += expf(-0.5f * sd[k]) * (1.0f - ps[si[k]]);
      atomicAdd(per_gt_sum, a * 0.2f);
      atomicOr(&bs_unm[bs], 1);
    }
  }
}

// Two-stage reduction: each block writes one partial row (no global atomics).
__global__ void __launch_bounds__(256) loss_kernel(
    const float* __restrict__ pred_boxes, const float* __restrict__ pred_scores,
    const float* __restrict__ gt_boxes, const int* __restrict__ assign,
    float* __restrict__ partials) {
  int tid = blockIdx.x * blockDim.x + threadIdx.x;
  const int total = NB * NS * NN;
  float lc = 0.0f, spp = 0.0f, spn = 0.0f, np = 0.0f;
  for (int i = tid; i < total; i += gridDim.x * blockDim.x) {
    int a = assign[i];
    float x = pred_scores[i];
    if (a >= 0) {
      np += 1.0f;
      int b = i / (NS * NN);
      const float* pbp = &pred_boxes[(size_t)i * 7];
      const float* gbp = &gt_boxes[(b * NM + a) * 7];
#pragma unroll
      for (int c = 0; c < 3; c++) {
        float diff = pbp[c] - gbp[c];
        float ad = fabsf(diff);
        lc += (ad < 1.0f) ? 0.5f * ad * ad : (ad - 0.5f);
      }
      // softplus(-x) = log1p(exp(-|x|)) + max(-x, 0)
      spp += log1pf(expf(-fabsf(x))) + fmaxf(-x, 0.0f);
    } else {
      // softplus(x) = log1p(exp(-|x|)) + max(x, 0)
      spn += log1pf(expf(-fabsf(x))) + fmaxf(x, 0.0f);
    }
  }
  // wave-64 shuffle reduce
#pragma unroll
  for (int off = 32; off >= 1; off >>= 1) {
    lc += __shfl_down(lc, off);
    spp += __shfl_down(spp, off);
    spn += __shfl_down(spn, off);
    np += __shfl_down(np, off);
  }
  __shared__ float red[4][4];
  int wave = threadIdx.x >> 6;
  if ((threadIdx.x & 63) == 0) {
    red[wave][0] = lc; red[wave][1] = spp; red[wave][2] = spn; red[wave][3] = np;
  }
  __syncthreads();
  if (threadIdx.x == 0) {
    float o0 = 0, o1 = 0, o2 = 0, o3 = 0;
#pragma unroll
    for (int w = 0; w < 4; w++) { o0 += red[w][0]; o1 += red[w][1]; o2 += red[w][2]; o3 += red[w][3]; }
    float* p = &partials[(size_t)blockIdx.x * 8];
    p[0] = o0; p[1] = o1; p[2] = o2; p[3] = o3;
  }
}

__global__ void __launch_bounds__(256) final_kernel(
    const float* __restrict__ partials, const float* __restrict__ acc,
    const int* __restrict__ bs_unm,
    const float* __restrict__ wc, const float* __restrict__ wo,
    const float* __restrict__ wu, float* __restrict__ out) {
  const int t = threadIdx.x;
  const float* p = &partials[(size_t)t * 8];
  float lc = p[0], spp = p[1], spn = p[2], np = p[3];
#pragma unroll
  for (int off = 32; off >= 1; off >>= 1) {
    lc += __shfl_down(lc, off);
    spp += __shfl_down(spp, off);
    spn += __shfl_down(spn, off);
    np += __shfl_down(np, off);
  }
  __shared__ float red[4][4];
  int wave = t >> 6;
  if ((t & 63) == 0) {
    red[wave][0] = lc; red[wave][1] = spp; red[wave][2] = spn; red[wave][3] = np;
  }
  __syncthreads();
  if (t == 0) {
    float o0 = 0, o1 = 0, o2 = 0, o3 = 0;
#pragma unroll
    for (int w = 0; w < 4; w++) { o0 += red[w][0]; o1 += red[w][1]; o2 += red[w][2]; o3 += red[w][3]; }
    int ne = 0;
    for (int i = 0; i < NB * NS; i++) ne += bs_unm[i];
    float n_pos = o3;
    float loss_center = o0 / fmaxf(n_pos * 3.0f, 1.0f);
    float n_neg = (float)(NB * NS * NN) - n_pos;
    float pw = fminf(10.0f, n_neg / fmaxf(n_pos, 1.0f));
    float loss_obj = (pw * o1 + o2) / (float)(NB * NS * NN);
    float loss_unm = acc[0] / fmaxf((float)ne, 1.0f);
    out[0] = loss_center * wc[0] + loss_obj * wo[0] + loss_unm * wu[0];
  }
}

extern "C" void kernel_launch(void* const* d_in, const int* in_sizes, int n_in,
                              void* d_out, int out_size, void* d_ws, size_t ws_size,
                              hipStream_t stream) {
  const float* pred_boxes = (const float*)d_in[0];
  // d_in[1] = pred_classes (unused), d_in[4] = gt_classes (unused), d_in[9] = epoch (unused)
  const float* pred_scores = (const float*)d_in[2];
  const float* gt_boxes = (const float*)d_in[3];
  const int* n_gt = (const int*)d_in[5];
  const float* wc = (const float*)d_in[6];
  const float* wo = (const float*)d_in[7];
  const float* wu = (const float*)d_in[8];
  float* out = (float*)d_out;

  char* ws = (char*)d_ws;
  int* assign = (int*)ws;                      ws += (size_t)NB * NS * NN * 4;  // 1 MB
  float* acc = (float*)ws;                     ws += 64;                        // [0]=per_gt_sum
  int* bs_unm = (int*)(ws - 64 + 32);          // 8..8+32 ints within the acc line region
  // keep layout simple: acc line is 64B: acc[0] float, then bs_unm after
  bs_unm = (int*)((char*)acc + 64);            ws = (char*)bs_unm + NB * NS * 4;
  // align partials to 256B
  float* partials = (float*)(((uintptr_t)ws + 255) & ~(uintptr_t)255);

  init_kernel<<<256, 256, 0, stream>>>(assign, acc, bs_unm);
  topk_kernel<<<NB * NS * NM, THREADS, 0, stream>>>(pred_boxes, pred_scores, gt_boxes,
                                                    n_gt, assign, &acc[0], bs_unm);
  loss_kernel<<<LOSS_BLOCKS, 256, 0, stream>>>(pred_boxes, pred_scores, gt_boxes, assign, partials);
  final_kernel<<<1, 256, 0, stream>>>(partials, acc, bs_unm, wc, wo, wu, out);
}

// Round 3
// 45.305 us; speedup vs baseline: 7.4000x; 2.9687x over previous
//
#include <hip/hip_runtime.h>

#define NB 8
#define NS 4
#define NN 8192
#define NM 50
#define K10 10
#define THREADS 256
#define COST_THRESH 50.0f
#define LOSS_BLOCKS 256
#define NBUCK 1024
#define CAP 1024

__device__ __forceinline__ bool lexless(float d1, int i1, float d2, int i2) {
  // matches jax.lax.top_k ordering on -dist: (dist asc, index asc)
  return (d1 < d2) || (d1 == d2 && i1 < i2);
}

__global__ void __launch_bounds__(256) init_kernel(int* __restrict__ assign,
                                                   float* __restrict__ acc,
                                                   int* __restrict__ bs_unm) {
  int i = blockIdx.x * blockDim.x + threadIdx.x;
  const int total = NB * NS * NN;
  for (int j = i; j < total; j += gridDim.x * blockDim.x) assign[j] = -1;
  if (i == 0) acc[0] = 0.0f;  // per_gt_sum
  if (i >= 64 && i < 64 + NB * NS) bs_unm[i - 64] = 0;
}

// One block per (b, s, m): exact top-10 nearest preds by (dist, idx) via
// histogram-select on d^2 (monotone in dist). masked top-10 = {entries with
// dist < 50} (subset property), unmatched top-5 = first 5 of raw top-10.
__global__ void __launch_bounds__(256) topk_kernel(
    const float* __restrict__ pred_boxes, const float* __restrict__ pred_scores,
    const float* __restrict__ gt_boxes, const int* __restrict__ n_gt,
    int* __restrict__ assign, float* __restrict__ per_gt_sum,
    int* __restrict__ bs_unm) {
  const int blk = blockIdx.x;      // b*NS*NM + s*NM + m
  const int m = blk % NM;
  const int bs = blk / NM;
  const int b = bs / NS;
  const int t = threadIdx.x;

  __shared__ float sd2[NN];        // 32 KB: d^2 per pred
  __shared__ int shist[NBUCK];     // 4 KB
  __shared__ float scd[CAP];       // candidate d^2 -> later sqrt'd dist
  __shared__ int sci[CAP];         // candidate idx
  __shared__ float sred[16];       // min/max staging
  __shared__ float sbb[2];         // bmin, scale
  __shared__ int scnt;
  __shared__ int sbucket;
  __shared__ float soutd[K10];
  __shared__ int souti[K10];

  for (int i = t; i < NBUCK; i += THREADS) shist[i] = 0;
  if (t == 0) { scnt = 0; sbucket = NBUCK - 2; }

  const float gx = gt_boxes[(b * NM + m) * 7 + 0];
  const float gy = gt_boxes[(b * NM + m) * 7 + 1];
  const float gz = gt_boxes[(b * NM + m) * 7 + 2];
  const bool valid = (m < n_gt[b]);

  // P1: d^2 for all preds -> LDS; track min/max
  const float* pb = pred_boxes + (size_t)bs * NN * 7;
  float lmin = INFINITY, lmax = 0.0f;
#pragma unroll
  for (int k = 0; k < NN / THREADS; k++) {
    int n = t + k * THREADS;
    float dx = pb[n * 7 + 0] - gx;
    float dy = pb[n * 7 + 1] - gy;
    float dz = pb[n * 7 + 2] - gz;
    float d2 = dx * dx + dy * dy + dz * dz;
    sd2[n] = d2;
    lmin = fminf(lmin, d2);
    lmax = fmaxf(lmax, d2);
  }
#pragma unroll
  for (int off = 32; off >= 1; off >>= 1) {
    lmin = fminf(lmin, __shfl_down(lmin, off));
    lmax = fmaxf(lmax, __shfl_down(lmax, off));
  }
  int wave = t >> 6;
  if ((t & 63) == 0) { sred[wave] = lmin; sred[8 + wave] = lmax; }
  __syncthreads();
  if (t == 0) {
    float bmin = fminf(fminf(sred[0], sred[1]), fminf(sred[2], sred[3]));
    float bmax = fmaxf(fmaxf(sred[8], sred[9]), fmaxf(sred[10], sred[11]));
    sbb[0] = bmin;
    sbb[1] = (float)NBUCK / fmaxf(bmax - bmin, 1e-30f);
  }
  __syncthreads();
  const float bmin = sbb[0], scale = sbb[1];

  // P2: histogram on d^2
#pragma unroll
  for (int k = 0; k < NN / THREADS; k++) {
    int n = t + k * THREADS;
    int bidx = (int)((sd2[n] - bmin) * scale);
    bidx = min(NBUCK - 1, max(0, bidx));
    atomicAdd(&shist[bidx], 1);
  }
  __syncthreads();

  // P3: first bucket j with cumulative count >= 10 (single wave)
  if (t < 64) {
    int lsum = 0;
    for (int i = 0; i < NBUCK / 64; i++) lsum += shist[t * (NBUCK / 64) + i];
    int incl = lsum;
#pragma unroll
    for (int off = 1; off < 64; off <<= 1) {
      int v = __shfl_up(incl, off);
      if (t >= off) incl += v;
    }
    int excl = incl - lsum;
    if (excl < K10 && incl >= K10) {
      int c = excl;
      for (int i = 0; i < NBUCK / 64; i++) {
        c += shist[t * (NBUCK / 64) + i];
        if (c >= K10) { sbucket = t * (NBUCK / 64) + i; break; }
      }
    }
  }
  __syncthreads();
  // hi-edge of bucket j+1 plus half-bin margin (covers edge rounding + sqrt-ties)
  const float bound = bmin + ((float)(sbucket + 2) + 0.5f) / scale;

  // P4: collect candidates below bound (superset of exact top-10)
#pragma unroll
  for (int k = 0; k < NN / THREADS; k++) {
    int n = t + k * THREADS;
    float d2 = sd2[n];
    if (d2 < bound) {
      int p = atomicAdd(&scnt, 1);
      if (p < CAP) { scd[p] = d2; sci[p] = n; }
    }
  }
  __syncthreads();
  const int K = min(scnt, CAP);

  // P5: sqrt candidates (matches reference dist exactly), exact rank by (d, idx)
  for (int c = t; c < K; c += THREADS) scd[c] = sqrtf(scd[c]);
  __syncthreads();
  for (int c = t; c < K; c += THREADS) {
    float dc = scd[c];
    int ic = sci[c];
    int rank = 0;
    for (int o = 0; o < K; o++) rank += lexless(scd[o], sci[o], dc, ic) ? 1 : 0;
    if (rank < K10) { soutd[rank] = dc; souti[rank] = ic; }
  }
  __syncthreads();

  if (t == 0) {
    bool matched = false;
#pragma unroll
    for (int k = 0; k < K10; k++) {
      if (valid && soutd[k] < COST_THRESH) {
        matched = true;
        atomicMax(&assign[(size_t)bs * NN + souti[k]], m);
      }
    }
    if (valid && !matched) {
      const float* ps = pred_scores + (size_t)bs * NN;
      float a = 0.0f;
#pragma unroll
      for (int k = 0; k < 5; k++) a += expf(-0.5f * soutd[k]) * (1.0f - ps[souti[k]]);
      atomicAdd(per_gt_sum, a * 0.2f);
      atomicOr(&bs_unm[bs], 1);
    }
  }
}

// Two-stage reduction: each block writes one partial row (no global atomics).
__global__ void __launch_bounds__(256) loss_kernel(
    const float* __restrict__ pred_boxes, const float* __restrict__ pred_scores,
    const float* __restrict__ gt_boxes, const int* __restrict__ assign,
    float* __restrict__ partials) {
  int tid = blockIdx.x * blockDim.x + threadIdx.x;
  const int total = NB * NS * NN;
  float lc = 0.0f, spp = 0.0f, spn = 0.0f, np = 0.0f;
  for (int i = tid; i < total; i += gridDim.x * blockDim.x) {
    int a = assign[i];
    float x = pred_scores[i];
    if (a >= 0) {
      np += 1.0f;
      int b = i / (NS * NN);
      const float* pbp = &pred_boxes[(size_t)i * 7];
      const float* gbp = &gt_boxes[(b * NM + a) * 7];
#pragma unroll
      for (int c = 0; c < 3; c++) {
        float diff = pbp[c] - gbp[c];
        float ad = fabsf(diff);
        lc += (ad < 1.0f) ? 0.5f * ad * ad : (ad - 0.5f);
      }
      spp += log1pf(expf(-fabsf(x))) + fmaxf(-x, 0.0f);  // softplus(-x)
    } else {
      spn += log1pf(expf(-fabsf(x))) + fmaxf(x, 0.0f);   // softplus(x)
    }
  }
#pragma unroll
  for (int off = 32; off >= 1; off >>= 1) {
    lc += __shfl_down(lc, off);
    spp += __shfl_down(spp, off);
    spn += __shfl_down(spn, off);
    np += __shfl_down(np, off);
  }
  __shared__ float red[4][4];
  int wave = threadIdx.x >> 6;
  if ((threadIdx.x & 63) == 0) {
    red[wave][0] = lc; red[wave][1] = spp; red[wave][2] = spn; red[wave][3] = np;
  }
  __syncthreads();
  if (threadIdx.x == 0) {
    float o0 = 0, o1 = 0, o2 = 0, o3 = 0;
#pragma unroll
    for (int w = 0; w < 4; w++) { o0 += red[w][0]; o1 += red[w][1]; o2 += red[w][2]; o3 += red[w][3]; }
    float* p = &partials[(size_t)blockIdx.x * 8];
    p[0] = o0; p[1] = o1; p[2] = o2; p[3] = o3;
  }
}

__global__ void __launch_bounds__(256) final_kernel(
    const float* __restrict__ partials, const float* __restrict__ acc,
    const int* __restrict__ bs_unm,
    const float* __restrict__ wc, const float* __restrict__ wo,
    const float* __restrict__ wu, float* __restrict__ out) {
  const int t = threadIdx.x;
  const float* p = &partials[(size_t)t * 8];
  float lc = p[0], spp = p[1], spn = p[2], np = p[3];
#pragma unroll
  for (int off = 32; off >= 1; off >>= 1) {
    lc += __shfl_down(lc, off);
    spp += __shfl_down(spp, off);
    spn += __shfl_down(spn, off);
    np += __shfl_down(np, off);
  }
  __shared__ float red[4][4];
  int wave = t >> 6;
  if ((t & 63) == 0) {
    red[wave][0] = lc; red[wave][1] = spp; red[wave][2] = spn; red[wave][3] = np;
  }
  __syncthreads();
  if (t == 0) {
    float o0 = 0, o1 = 0, o2 = 0, o3 = 0;
#pragma unroll
    for (int w = 0; w < 4; w++) { o0 += red[w][0]; o1 += red[w][1]; o2 += red[w][2]; o3 += red[w][3]; }
    int ne = 0;
    for (int i = 0; i < NB * NS; i++) ne += bs_unm[i];
    float n_pos = o3;
    float loss_center = o0 / fmaxf(n_pos * 3.0f, 1.0f);
    float n_neg = (float)(NB * NS * NN) - n_pos;
    float pw = fminf(10.0f, n_neg / fmaxf(n_pos, 1.0f));
    float loss_obj = (pw * o1 + o2) / (float)(NB * NS * NN);
    float loss_unm = acc[0] / fmaxf((float)ne, 1.0f);
    out[0] = loss_center * wc[0] + loss_obj * wo[0] + loss_unm * wu[0];
  }
}

extern "C" void kernel_launch(void* const* d_in, const int* in_sizes, int n_in,
                              void* d_out, int out_size, void* d_ws, size_t ws_size,
                              hipStream_t stream) {
  const float* pred_boxes = (const float*)d_in[0];
  // d_in[1] = pred_classes (unused), d_in[4] = gt_classes (unused), d_in[9] = epoch (unused)
  const float* pred_scores = (const float*)d_in[2];
  const float* gt_boxes = (const float*)d_in[3];
  const int* n_gt = (const int*)d_in[5];
  const float* wc = (const float*)d_in[6];
  const float* wo = (const float*)d_in[7];
  const float* wu = (const float*)d_in[8];
  float* out = (float*)d_out;

  char* ws = (char*)d_ws;
  int* assign = (int*)ws;                  // NB*NS*NN ints (1 MB)
  float* acc = (float*)(ws + (size_t)NB * NS * NN * 4);  // acc[0] = per_gt_sum (own 64B line)
  int* bs_unm = (int*)((char*)acc + 256);  // NB*NS ints
  float* partials = (float*)((char*)bs_unm + 256);  // LOSS_BLOCKS * 8 floats

  init_kernel<<<256, 256, 0, stream>>>(assign, acc, bs_unm);
  topk_kernel<<<NB * NS * NM, THREADS, 0, stream>>>(pred_boxes, pred_scores, gt_boxes,
                                                    n_gt, assign, &acc[0], bs_unm);
  loss_kernel<<<LOSS_BLOCKS, 256, 0, stream>>>(pred_boxes, pred_scores, gt_boxes, assign, partials);
  final_kernel<<<1, 256, 0, stream>>>(partials, acc, bs_unm, wc, wo, wu, out);
}